// Round 5
// baseline (147.644 us; speedup 1.0000x reference)
//
#include <hip/hip_runtime.h>
#include <hip/hip_fp16.h>

#define N_NODES 50000
#define N_EDGES 100000
#define EDGE_DIM 8
#define EHID 32
#define DIN 32
#define H1 32
#define H2 64
#define NGRAPH 256
#define BN_EPS 1e-5f
#define KTOT 1056   // EHID*DIN + DIN (b2 rows appended as slice 32)
#define MAXDEG 32

#define EH_BLOCKS  ((N_EDGES + 255) / 256)        // 391
#define PREP_TOTAL ((H1 + H2) * KTOT)             // 101376
#define PREP_BLOCKS (PREP_TOTAL / 256)            // 396 exact
#define INIT_BLOCKS 16
#define MSG_BLOCKS 512

typedef __attribute__((ext_vector_type(8))) _Float16 f16x8;
typedef __attribute__((ext_vector_type(4))) float f32x4;
typedef unsigned int uint32;

// ---------------------------------------------------------------- utilities
__device__ inline void atomicMaxF(float* addr, float v) {
    if (v >= 0.0f) atomicMax((int*)addr, __float_as_int(v));
    else           atomicMin((unsigned int*)addr, __float_as_uint(v));
}

__device__ inline uint32 pk_f16(float a, float b) {
    uint32 r;
    asm("v_cvt_pkrtz_f16_f32 %0, %1, %2" : "=v"(r) : "v"(a), "v"(b));
    return r;
}

union GF { uint32 u[4]; f16x8 v; };

__device__ inline f16x8 mul_h(uint32 h, const GF& g) {
    GF r;
    asm("v_pk_mul_f16 %0, %1, %2" : "=v"(r.u[0]) : "v"(h), "v"(g.u[0]));
    asm("v_pk_mul_f16 %0, %1, %2" : "=v"(r.u[1]) : "v"(h), "v"(g.u[1]));
    asm("v_pk_mul_f16 %0, %1, %2" : "=v"(r.u[2]) : "v"(h), "v"(g.u[2]));
    asm("v_pk_mul_f16 %0, %1, %2" : "=v"(r.u[3]) : "v"(h), "v"(g.u[3]));
    return r.v;
}

// ---------------------------------------------------------------- prologue:
// edge MLP (both layers) + edge-table build + w2->f16 transpose + pool-buf init
__global__ __launch_bounds__(256) void prologue_kernel(
    const float* __restrict__ edge_attr, const int* __restrict__ dstp,
    const float* __restrict__ e1w1, const float* __restrict__ e1b1,
    const float* __restrict__ e2w1, const float* __restrict__ e2b1,
    const float* __restrict__ e1w2, const float* __restrict__ e1b2,
    const float* __restrict__ e2w2, const float* __restrict__ e2b2,
    uint32* __restrict__ hpk1, uint32* __restrict__ hpk2,
    unsigned short* __restrict__ w2h1, unsigned short* __restrict__ w2h2,
    int* __restrict__ deg, int* __restrict__ etab,
    float* __restrict__ gmax, float* __restrict__ gsum, float* __restrict__ gcnt)
{
    int bid = blockIdx.x, tid = threadIdx.x;
    if (bid < EH_BLOCKS) {
        __shared__ float s_w[2][EDGE_DIM * EHID];
        __shared__ float s_b[2][EHID];
        if (tid < EDGE_DIM * EHID) { s_w[0][tid] = e1w1[tid]; s_w[1][tid] = e2w1[tid]; }
        if (tid < EHID) { s_b[0][tid] = e1b1[tid]; s_b[1][tid] = e2b1[tid]; }
        __syncthreads();
        int e = bid * 256 + tid;
        if (e >= N_EDGES) return;
        // build gather table (deg pre-zeroed via memset)
        int d = dstp[e];
        int slot = atomicAdd(&deg[d], 1);
        if (slot < MAXDEG) etab[(size_t)d * MAXDEG + slot] = e;
        // edge MLP, both layers, h stored as duplicated-half2 u32
        const float4* eap = reinterpret_cast<const float4*>(edge_attr + (size_t)e * EDGE_DIM);
        float4 v0 = eap[0], v1 = eap[1];
        float ea[EDGE_DIM] = {v0.x, v0.y, v0.z, v0.w, v1.x, v1.y, v1.z, v1.w};
#pragma unroll
        for (int L = 0; L < 2; ++L) {
            uint32* hp = (L == 0 ? hpk1 : hpk2) + (size_t)e * EHID;
#pragma unroll
            for (int k4 = 0; k4 < EHID; k4 += 4) {
                uint32 t[4];
#pragma unroll
                for (int q = 0; q < 4; ++q) {
                    int k = k4 + q;
                    float acc = s_b[L][k];
#pragma unroll
                    for (int j = 0; j < EDGE_DIM; ++j) acc += ea[j] * s_w[L][j * EHID + k];
                    acc = fmaxf(acc, 0.0f);
                    t[q] = pk_f16(acc, acc);
                }
                uint4 r; r.x = t[0]; r.y = t[1]; r.z = t[2]; r.w = t[3];
                *reinterpret_cast<uint4*>(hp + k4) = r;
            }
        }
    } else if (bid < EH_BLOCKS + PREP_BLOCKS) {
        int idx = (bid - EH_BLOCKS) * 256 + tid;
        const int n1 = H1 * KTOT;
        if (idx < n1) {
            int o = idx / KTOT, k = idx % KTOT;
            float v = (k < EHID * DIN) ? e1w2[(k >> 5) * (DIN * H1) + (k & 31) * H1 + o]
                                       : e1b2[(k - EHID * DIN) * H1 + o];
            w2h1[idx] = __half_as_ushort(__float2half(v));
        } else {
            int j = idx - n1;
            int o = j / KTOT, k = j % KTOT;
            float v = (k < EHID * DIN) ? e2w2[(k >> 5) * (DIN * H2) + (k & 31) * H2 + o]
                                       : e2b2[(k - EHID * DIN) * H2 + o];
            w2h2[j] = __half_as_ushort(__float2half(v));
        }
    } else {
        int lb = bid - EH_BLOCKS - PREP_BLOCKS;
        int stride = INIT_BLOCKS * 256;
        int i0 = lb * 256 + tid;
        for (int i = i0; i < NGRAPH * H2; i += stride) { gmax[i] = __int_as_float(0xff800000); gsum[i] = 0.0f; }
        for (int i = i0; i < NGRAPH; i += stride) gcnt[i] = 0.0f;
    }
}

// ---------------------------------------------------------------- MFMA message, v5:
// B-in-registers, zero barriers, 32 edges/iter (2 chains), 2-deep pipelined loads,
// plain coalesced stores of msg[e][o] (NO atomics).
template <int DOUT>
__global__ __launch_bounds__(256, 2) void msg_v5_kernel(
    const float* __restrict__ gsrc,          // [N, 32]
    const uint32* __restrict__ hpk,          // [E, 32] duplicated-half2
    const int* __restrict__ src,
    const unsigned short* __restrict__ w2h,  // f16 [DOUT][KTOT]
    float* __restrict__ msg)                 // [E, DOUT]
{
    constexpr int NT = DOUT / 16;
    __shared__ __align__(16) uint32 hlds[4][2][32][36];

    const int tid = threadIdx.x;
    const int wave = tid >> 6;
    const int lane = tid & 63;
    const int col = lane & 15;
    const int kq = lane >> 4;

    const int w = blockIdx.x * 4 + wave;
    const int ot = w % NT;
    int it = w / NT;
    const int strideIt = (MSG_BLOCKS * 4) / NT;
    const int NIT = N_EDGES / 32;            // 3125 exact

    f16x8 B[33];
    {
        const unsigned short* bp = w2h + (size_t)(ot * 16 + col) * KTOT + kq * 8;
#pragma unroll
        for (int kk = 0; kk < 33; ++kk)
            B[kk] = *reinterpret_cast<const f16x8*>(bp + kk * 32);
    }
    if (it >= NIT) return;

    int buf = 0;

    int e0 = it * 32;
    int sA = src[e0 + col], sB = src[e0 + 16 + col];
    float4 gA0 = *reinterpret_cast<const float4*>(gsrc + (size_t)sA * DIN + kq * 8);
    float4 gA1 = *reinterpret_cast<const float4*>(gsrc + (size_t)sA * DIN + kq * 8 + 4);
    float4 gB0 = *reinterpret_cast<const float4*>(gsrc + (size_t)sB * DIN + kq * 8);
    float4 gB1 = *reinterpret_cast<const float4*>(gsrc + (size_t)sB * DIN + kq * 8 + 4);
    uint4 hA0 = *reinterpret_cast<const uint4*>(hpk + (size_t)(e0 + col) * EHID + kq * 8);
    uint4 hA1 = *reinterpret_cast<const uint4*>(hpk + (size_t)(e0 + col) * EHID + kq * 8 + 4);
    uint4 hB0 = *reinterpret_cast<const uint4*>(hpk + (size_t)(e0 + 16 + col) * EHID + kq * 8);
    uint4 hB1 = *reinterpret_cast<const uint4*>(hpk + (size_t)(e0 + 16 + col) * EHID + kq * 8 + 4);

    int it1 = it + strideIt;
    int s1A = 0, s1B = 0;
    if (it1 < NIT) { s1A = src[it1 * 32 + col]; s1B = src[it1 * 32 + 16 + col]; }

    GF gfA, gfB;
    gfA.u[0] = pk_f16(gA0.x, gA0.y); gfA.u[1] = pk_f16(gA0.z, gA0.w);
    gfA.u[2] = pk_f16(gA1.x, gA1.y); gfA.u[3] = pk_f16(gA1.z, gA1.w);
    gfB.u[0] = pk_f16(gB0.x, gB0.y); gfB.u[1] = pk_f16(gB0.z, gB0.w);
    gfB.u[2] = pk_f16(gB1.x, gB1.y); gfB.u[3] = pk_f16(gB1.z, gB1.w);
    *reinterpret_cast<uint4*>(&hlds[wave][0][col][kq * 8])          = hA0;
    *reinterpret_cast<uint4*>(&hlds[wave][0][col][kq * 8 + 4])      = hA1;
    *reinterpret_cast<uint4*>(&hlds[wave][0][16 + col][kq * 8])     = hB0;
    *reinterpret_cast<uint4*>(&hlds[wave][0][16 + col][kq * 8 + 4]) = hB1;

    for (;;) {
        int it2 = it1 + strideIt;
        int s2A = 0, s2B = 0;
        if (it2 < NIT) { s2A = src[it2 * 32 + col]; s2B = src[it2 * 32 + 16 + col]; }

        const bool nv = (it1 < NIT);
        float4 ngA0, ngA1, ngB0, ngB1;
        uint4 nhA0, nhA1, nhB0, nhB1;
        if (nv) {
            int ne0 = it1 * 32;
            ngA0 = *reinterpret_cast<const float4*>(gsrc + (size_t)s1A * DIN + kq * 8);
            ngA1 = *reinterpret_cast<const float4*>(gsrc + (size_t)s1A * DIN + kq * 8 + 4);
            ngB0 = *reinterpret_cast<const float4*>(gsrc + (size_t)s1B * DIN + kq * 8);
            ngB1 = *reinterpret_cast<const float4*>(gsrc + (size_t)s1B * DIN + kq * 8 + 4);
            nhA0 = *reinterpret_cast<const uint4*>(hpk + (size_t)(ne0 + col) * EHID + kq * 8);
            nhA1 = *reinterpret_cast<const uint4*>(hpk + (size_t)(ne0 + col) * EHID + kq * 8 + 4);
            nhB0 = *reinterpret_cast<const uint4*>(hpk + (size_t)(ne0 + 16 + col) * EHID + kq * 8);
            nhB1 = *reinterpret_cast<const uint4*>(hpk + (size_t)(ne0 + 16 + col) * EHID + kq * 8 + 4);
        }

        f32x4 accA = (f32x4){0.f, 0.f, 0.f, 0.f};
        f32x4 accB = (f32x4){0.f, 0.f, 0.f, 0.f};
#pragma unroll
        for (int t = 0; t < 8; ++t) {
            uint4 ha = *reinterpret_cast<const uint4*>(&hlds[wave][buf][col][t * 4]);
            uint4 hb = *reinterpret_cast<const uint4*>(&hlds[wave][buf][16 + col][t * 4]);
            accA = __builtin_amdgcn_mfma_f32_16x16x32_f16(mul_h(ha.x, gfA), B[t * 4 + 0], accA, 0, 0, 0);
            accB = __builtin_amdgcn_mfma_f32_16x16x32_f16(mul_h(hb.x, gfB), B[t * 4 + 0], accB, 0, 0, 0);
            accA = __builtin_amdgcn_mfma_f32_16x16x32_f16(mul_h(ha.y, gfA), B[t * 4 + 1], accA, 0, 0, 0);
            accB = __builtin_amdgcn_mfma_f32_16x16x32_f16(mul_h(hb.y, gfB), B[t * 4 + 1], accB, 0, 0, 0);
            accA = __builtin_amdgcn_mfma_f32_16x16x32_f16(mul_h(ha.z, gfA), B[t * 4 + 2], accA, 0, 0, 0);
            accB = __builtin_amdgcn_mfma_f32_16x16x32_f16(mul_h(hb.z, gfB), B[t * 4 + 2], accB, 0, 0, 0);
            accA = __builtin_amdgcn_mfma_f32_16x16x32_f16(mul_h(ha.w, gfA), B[t * 4 + 3], accA, 0, 0, 0);
            accB = __builtin_amdgcn_mfma_f32_16x16x32_f16(mul_h(hb.w, gfB), B[t * 4 + 3], accB, 0, 0, 0);
        }
        accA = __builtin_amdgcn_mfma_f32_16x16x32_f16(gfA.v, B[32], accA, 0, 0, 0);
        accB = __builtin_amdgcn_mfma_f32_16x16x32_f16(gfB.v, B[32], accB, 0, 0, 0);

        // plain stores: msg[e][ot*16+col], e = e0 + (kq*4+r) (+16 for chain B)
        {
            const int oc = ot * 16 + col;
#pragma unroll
            for (int r = 0; r < 4; ++r)
                msg[(size_t)(e0 + kq * 4 + r) * DOUT + oc] = accA[r];
#pragma unroll
            for (int r = 0; r < 4; ++r)
                msg[(size_t)(e0 + 16 + kq * 4 + r) * DOUT + oc] = accB[r];
        }

        if (!nv) break;

        buf ^= 1;
        *reinterpret_cast<uint4*>(&hlds[wave][buf][col][kq * 8])          = nhA0;
        *reinterpret_cast<uint4*>(&hlds[wave][buf][col][kq * 8 + 4])      = nhA1;
        *reinterpret_cast<uint4*>(&hlds[wave][buf][16 + col][kq * 8])     = nhB0;
        *reinterpret_cast<uint4*>(&hlds[wave][buf][16 + col][kq * 8 + 4]) = nhB1;
        gfA.u[0] = pk_f16(ngA0.x, ngA0.y); gfA.u[1] = pk_f16(ngA0.z, ngA0.w);
        gfA.u[2] = pk_f16(ngA1.x, ngA1.y); gfA.u[3] = pk_f16(ngA1.z, ngA1.w);
        gfB.u[0] = pk_f16(ngB0.x, ngB0.y); gfB.u[1] = pk_f16(ngB0.z, ngB0.w);
        gfB.u[2] = pk_f16(ngB1.x, ngB1.y); gfB.u[3] = pk_f16(ngB1.z, ngB1.w);
        s1A = s2A; s1B = s2B;
        e0 = it1 * 32;
        it = it1; it1 = it2;
    }
}

// ---------------------------------------------------------------- fused gather + node update:
// out[n,o] = act( in[n]@root[:,o] + bias[o] + sum_{e in etab[n]} msg[e,o] )
template <int DOUTN, bool RELU>
__global__ __launch_bounds__(256) void gather_update_kernel(
    const float* __restrict__ in, const float* __restrict__ root,
    const float* __restrict__ msg, const int* __restrict__ deg,
    const int* __restrict__ etab, const float* __restrict__ bias,
    float* __restrict__ out)
{
    constexpr int NPB = 256 / DOUTN;
    __shared__ float roots[DIN * DOUTN];
    __shared__ float ins[NPB][DIN + 1];
    int tid = threadIdx.x;
    for (int idx = tid; idx < DIN * DOUTN; idx += 256) roots[idx] = root[idx];
    int o = tid % DOUTN, nl = tid / DOUTN;
    float bo = bias[o];
    const int nchunks = (N_NODES + NPB - 1) / NPB;
    for (int c = blockIdx.x; c < nchunks; c += gridDim.x) {
        int nBase = c * NPB;
        __syncthreads();
        for (int idx = tid; idx < NPB * DIN; idx += 256) {
            int nn = nBase + idx / DIN;
            ins[idx / DIN][idx % DIN] = (nn < N_NODES) ? in[(size_t)nn * DIN + (idx % DIN)] : 0.0f;
        }
        __syncthreads();
        int n = nBase + nl;
        if (n < N_NODES) {
            float t = bo;
#pragma unroll
            for (int i = 0; i < DIN; ++i) t += ins[nl][i] * roots[i * DOUTN + o];
            int dg = deg[n]; if (dg > MAXDEG) dg = MAXDEG;
            const int* ep = etab + (size_t)n * MAXDEG;
            for (int j = 0; j < dg; ++j) {
                int e = ep[j];  // same addr across the node's lanes -> broadcast
                t += msg[(size_t)e * DOUTN + o];
            }
            if (RELU) t = fmaxf(t, 0.0f);
            out[(size_t)n * DOUTN + o] = t;
        }
    }
}

// ---------------------------------------------------------------- pooling: sorted-run scan
__global__ __launch_bounds__(256) void pool_scan_kernel(
    const float* __restrict__ h, const int* __restrict__ batch,
    float* gmax, float* gsum, float* gcnt)
{
    __shared__ int s_batch[64];
    int tid = threadIdx.x;
    int base = blockIdx.x * 64;
    if (tid < 64) s_batch[tid] = (base + tid < N_NODES) ? batch[base + tid] : -1;
    __syncthreads();
    int o = tid & 63, r = tid >> 6;
    int curb = -1; float s = 0.f, m = __int_as_float(0xff800000); float c = 0.f;
#pragma unroll
    for (int j = 0; j < 16; ++j) {
        int n = base + r * 16 + j;
        if (n >= N_NODES) break;
        int b = s_batch[r * 16 + j];
        if (b != curb) {
            if (curb >= 0) {
                atomicAdd(&gsum[curb * H2 + o], s);
                atomicMaxF(&gmax[curb * H2 + o], m);
                if (o == 0) atomicAdd(&gcnt[curb], c);
            }
            curb = b; s = 0.f; m = __int_as_float(0xff800000); c = 0.f;
        }
        float v = h[(size_t)n * H2 + o];
        s += v; m = fmaxf(m, v); c += 1.f;
    }
    if (curb >= 0) {
        atomicAdd(&gsum[curb * H2 + o], s);
        atomicMaxF(&gmax[curb * H2 + o], m);
        if (o == 0) atomicAdd(&gcnt[curb], c);
    }
}

// ---------------------------------------------------------------- MLP head
__global__ __launch_bounds__(128) void head_kernel(
    const float* __restrict__ gmax, const float* __restrict__ gsum, const float* __restrict__ gcnt,
    const float* __restrict__ h1w, const float* __restrict__ h1b,
    const float* __restrict__ bn1g, const float* __restrict__ bn1b,
    const float* __restrict__ bn1m, const float* __restrict__ bn1v,
    const float* __restrict__ h2w, const float* __restrict__ h2b,
    const float* __restrict__ bn2g, const float* __restrict__ bn2b,
    const float* __restrict__ bn2m, const float* __restrict__ bn2v,
    const float* __restrict__ h3w, const float* __restrict__ h3b,
    float* __restrict__ out)
{
    __shared__ float feat[2 * H2];
    __shared__ float z1s[H2];
    __shared__ float z2s[H2 / 2];
    int b = blockIdx.x, tid = threadIdx.x;
    float cnt = fmaxf(gcnt[b], 1.0f);
    if (tid < H2) feat[tid] = gmax[b * H2 + tid];
    else          feat[tid] = gsum[b * H2 + (tid - H2)] / cnt;
    __syncthreads();
    if (tid < H2) {
        float acc = h1b[tid];
#pragma unroll
        for (int j = 0; j < 2 * H2; ++j) acc += feat[j] * h1w[j * H2 + tid];
        acc = (acc - bn1m[tid]) * rsqrtf(bn1v[tid] + BN_EPS) * bn1g[tid] + bn1b[tid];
        z1s[tid] = fmaxf(acc, 0.0f);
    }
    __syncthreads();
    if (tid < H2 / 2) {
        float acc = h2b[tid];
#pragma unroll
        for (int j = 0; j < H2; ++j) acc += z1s[j] * h2w[j * (H2 / 2) + tid];
        acc = (acc - bn2m[tid]) * rsqrtf(bn2v[tid] + BN_EPS) * bn2g[tid] + bn2b[tid];
        z2s[tid] = fmaxf(acc, 0.0f);
    }
    __syncthreads();
    if (tid == 0) {
        float acc = h3b[0];
#pragma unroll
        for (int j = 0; j < H2 / 2; ++j) acc += z2s[j] * h3w[j];
        out[b] = acc;
    }
}

// ---------------------------------------------------------------- launch
extern "C" void kernel_launch(void* const* d_in, const int* in_sizes, int n_in,
                              void* d_out, int out_size, void* d_ws, size_t ws_size,
                              hipStream_t stream)
{
    const float* x         = (const float*)d_in[0];
    const int*   ei        = (const int*)d_in[1];
    const float* edge_attr = (const float*)d_in[2];
    const int*   batch     = (const int*)d_in[3];
    const float* e1_w1 = (const float*)d_in[4];
    const float* e1_b1 = (const float*)d_in[5];
    const float* e1_w2 = (const float*)d_in[6];
    const float* e1_b2 = (const float*)d_in[7];
    const float* root1 = (const float*)d_in[8];
    const float* bias1 = (const float*)d_in[9];
    const float* e2_w1 = (const float*)d_in[10];
    const float* e2_b1 = (const float*)d_in[11];
    const float* e2_w2 = (const float*)d_in[12];
    const float* e2_b2 = (const float*)d_in[13];
    const float* root2 = (const float*)d_in[14];
    const float* bias2 = (const float*)d_in[15];
    const float* h1w = (const float*)d_in[16];
    const float* h1b = (const float*)d_in[17];
    const float* bn1g = (const float*)d_in[18];
    const float* bn1b = (const float*)d_in[19];
    const float* bn1m = (const float*)d_in[20];
    const float* bn1v = (const float*)d_in[21];
    const float* h2w = (const float*)d_in[22];
    const float* h2b = (const float*)d_in[23];
    const float* bn2g = (const float*)d_in[24];
    const float* bn2b = (const float*)d_in[25];
    const float* bn2m = (const float*)d_in[26];
    const float* bn2v = (const float*)d_in[27];
    const float* h3w = (const float*)d_in[28];
    const float* h3b = (const float*)d_in[29];
    float* out = (float*)d_out;

    float* ws = (float*)d_ws;
    uint32* hpk1 = (uint32*)ws;                              // E*32 u32
    uint32* hpk2 = hpk1 + (size_t)N_EDGES * EHID;            // E*32 u32
    float* msg1  = (float*)(hpk2 + (size_t)N_EDGES * EHID);  // E*H1
    float* msg2  = msg1 + (size_t)N_EDGES * H1;              // E*H2
    float* out1  = msg2 + (size_t)N_EDGES * H2;              // N*H1
    float* h2o   = out1 + (size_t)N_NODES * H1;              // N*H2
    float* gmaxb = h2o + (size_t)N_NODES * H2;               // NGRAPH*H2
    float* gsumb = gmaxb + NGRAPH * H2;                      // NGRAPH*H2
    float* gcntb = gsumb + NGRAPH * H2;                      // NGRAPH (+pad)
    int*   degp  = (int*)(gcntb + 256);                      // N
    int*   etab  = degp + N_NODES;                           // N*MAXDEG
    unsigned short* w2h1 = (unsigned short*)(etab + (size_t)N_NODES * MAXDEG); // H1*KTOT
    unsigned short* w2h2 = w2h1 + (size_t)H1 * KTOT;                           // H2*KTOT

    const int* srcp = ei;
    const int* dstp = ei + N_EDGES;

    hipMemsetAsync(degp, 0, (size_t)N_NODES * sizeof(int), stream);

    prologue_kernel<<<EH_BLOCKS + PREP_BLOCKS + INIT_BLOCKS, 256, 0, stream>>>(
        edge_attr, dstp, e1_w1, e1_b1, e2_w1, e2_b1, e1_w2, e1_b2, e2_w2, e2_b2,
        hpk1, hpk2, w2h1, w2h2, degp, etab, gmaxb, gsumb, gcntb);

    msg_v5_kernel<H1><<<MSG_BLOCKS, 256, 0, stream>>>(x, hpk1, srcp, w2h1, msg1);
    gather_update_kernel<H1, true><<<1024, 256, 0, stream>>>(x, root1, msg1, degp, etab, bias1, out1);

    msg_v5_kernel<H2><<<MSG_BLOCKS, 256, 0, stream>>>(out1, hpk2, srcp, w2h2, msg2);
    gather_update_kernel<H2, false><<<1024, 256, 0, stream>>>(out1, root2, msg2, degp, etab, bias2, h2o);

    pool_scan_kernel<<<(N_NODES + 63) / 64, 256, 0, stream>>>(h2o, batch, gmaxb, gsumb, gcntb);
    head_kernel<<<NGRAPH, 128, 0, stream>>>(gmaxb, gsumb, gcntb,
                                            h1w, h1b, bn1g, bn1b, bn1m, bn1v,
                                            h2w, h2b, bn2g, bn2b, bn2m, bn2v,
                                            h3w, h3b, out);
}

// Round 6
// 109.565 us; speedup vs baseline: 1.3476x; 1.3476x over previous
//
#include <hip/hip_runtime.h>
#include <hip/hip_fp16.h>

#define N_NODES 50000
#define N_EDGES 100000
#define EDGE_DIM 8
#define EHID 32
#define DIN 32
#define H1 32
#define H2 64
#define NGRAPH 256
#define BN_EPS 1e-5f
#define KTOT 1056   // EHID*DIN + DIN (b2 rows appended as slice 32)

#define EH_BLOCKS  ((N_EDGES + 255) / 256)        // 391
#define PREP_TOTAL ((H1 + H2) * KTOT)             // 101376
#define PREP_BLOCKS (PREP_TOTAL / 256)            // 396 exact
#define NU1_BLOCKS 512
#define INIT_BLOCKS 128
#define MSG_BLOCKS 512

typedef __attribute__((ext_vector_type(8))) _Float16 f16x8;
typedef __attribute__((ext_vector_type(4))) float f32x4;
typedef unsigned int uint32;

// ---------------------------------------------------------------- utilities
__device__ inline void atomicMaxF(float* addr, float v) {
    if (v >= 0.0f) atomicMax((int*)addr, __float_as_int(v));
    else           atomicMin((unsigned int*)addr, __float_as_uint(v));
}

__device__ inline uint32 pk_f16(float a, float b) {
    uint32 r;
    asm("v_cvt_pkrtz_f16_f32 %0, %1, %2" : "=v"(r) : "v"(a), "v"(b));
    return r;
}

union GF { uint32 u[4]; f16x8 v; };

template <bool RELUG>
__device__ inline GF pack_g8(float4 a, float4 b) {
    if (RELUG) {
        a.x = fmaxf(a.x, 0.f); a.y = fmaxf(a.y, 0.f); a.z = fmaxf(a.z, 0.f); a.w = fmaxf(a.w, 0.f);
        b.x = fmaxf(b.x, 0.f); b.y = fmaxf(b.y, 0.f); b.z = fmaxf(b.z, 0.f); b.w = fmaxf(b.w, 0.f);
    }
    GF gf;
    gf.u[0] = pk_f16(a.x, a.y); gf.u[1] = pk_f16(a.z, a.w);
    gf.u[2] = pk_f16(b.x, b.y); gf.u[3] = pk_f16(b.z, b.w);
    return gf;
}

__device__ inline f16x8 mul_h(uint32 h, const GF& g) {
    GF r;
    asm("v_pk_mul_f16 %0, %1, %2" : "=v"(r.u[0]) : "v"(h), "v"(g.u[0]));
    asm("v_pk_mul_f16 %0, %1, %2" : "=v"(r.u[1]) : "v"(h), "v"(g.u[1]));
    asm("v_pk_mul_f16 %0, %1, %2" : "=v"(r.u[2]) : "v"(h), "v"(g.u[2]));
    asm("v_pk_mul_f16 %0, %1, %2" : "=v"(r.u[3]) : "v"(h), "v"(g.u[3]));
    return r.v;
}

// ---------------------------------------------------------------- prologue:
// A: edge MLP both layers -> hpk (duplicated-half2 f16)
// B: w2+b2 -> f16 [DOUT][KTOT]
// C: agg1 = x@root1 + bias1  (root term pre-seeded; msg1 atomics add on top)
// D: agg2 = 0, pool buffers init
__global__ __launch_bounds__(256) void prologue_kernel(
    const float* __restrict__ edge_attr,
    const float* __restrict__ e1w1, const float* __restrict__ e1b1,
    const float* __restrict__ e2w1, const float* __restrict__ e2b1,
    const float* __restrict__ e1w2, const float* __restrict__ e1b2,
    const float* __restrict__ e2w2, const float* __restrict__ e2b2,
    const float* __restrict__ x, const float* __restrict__ root1,
    const float* __restrict__ bias1,
    uint32* __restrict__ hpk1, uint32* __restrict__ hpk2,
    unsigned short* __restrict__ w2h1, unsigned short* __restrict__ w2h2,
    float* __restrict__ agg1, float* __restrict__ agg2,
    float* __restrict__ gmax, float* __restrict__ gsum, float* __restrict__ gcnt)
{
    int bid = blockIdx.x, tid = threadIdx.x;
    if (bid < EH_BLOCKS) {
        __shared__ float s_w[2][EDGE_DIM * EHID];
        __shared__ float s_b[2][EHID];
        if (tid < EDGE_DIM * EHID) { s_w[0][tid] = e1w1[tid]; s_w[1][tid] = e2w1[tid]; }
        if (tid < EHID) { s_b[0][tid] = e1b1[tid]; s_b[1][tid] = e2b1[tid]; }
        __syncthreads();
        int e = bid * 256 + tid;
        if (e >= N_EDGES) return;
        const float4* eap = reinterpret_cast<const float4*>(edge_attr + (size_t)e * EDGE_DIM);
        float4 v0 = eap[0], v1 = eap[1];
        float ea[EDGE_DIM] = {v0.x, v0.y, v0.z, v0.w, v1.x, v1.y, v1.z, v1.w};
#pragma unroll
        for (int L = 0; L < 2; ++L) {
            uint32* hp = (L == 0 ? hpk1 : hpk2) + (size_t)e * EHID;
#pragma unroll
            for (int k4 = 0; k4 < EHID; k4 += 4) {
                uint32 t[4];
#pragma unroll
                for (int q = 0; q < 4; ++q) {
                    int k = k4 + q;
                    float acc = s_b[L][k];
#pragma unroll
                    for (int j = 0; j < EDGE_DIM; ++j) acc += ea[j] * s_w[L][j * EHID + k];
                    acc = fmaxf(acc, 0.0f);
                    t[q] = pk_f16(acc, acc);
                }
                uint4 r; r.x = t[0]; r.y = t[1]; r.z = t[2]; r.w = t[3];
                *reinterpret_cast<uint4*>(hp + k4) = r;
            }
        }
    } else if (bid < EH_BLOCKS + PREP_BLOCKS) {
        int idx = (bid - EH_BLOCKS) * 256 + tid;
        const int n1 = H1 * KTOT;
        if (idx < n1) {
            int o = idx / KTOT, k = idx % KTOT;
            float v = (k < EHID * DIN) ? e1w2[(k >> 5) * (DIN * H1) + (k & 31) * H1 + o]
                                       : e1b2[(k - EHID * DIN) * H1 + o];
            w2h1[idx] = __half_as_ushort(__float2half(v));
        } else {
            int j = idx - n1;
            int o = j / KTOT, k = j % KTOT;
            float v = (k < EHID * DIN) ? e2w2[(k >> 5) * (DIN * H2) + (k & 31) * H2 + o]
                                       : e2b2[(k - EHID * DIN) * H2 + o];
            w2h2[j] = __half_as_ushort(__float2half(v));
        }
    } else if (bid < EH_BLOCKS + PREP_BLOCKS + NU1_BLOCKS) {
        // agg1 = x @ root1 + bias1
        __shared__ float roots[DIN * H1];
        __shared__ float ins[8][DIN + 1];
        int lb = bid - EH_BLOCKS - PREP_BLOCKS;
        for (int idx = tid; idx < DIN * H1; idx += 256) roots[idx] = root1[idx];
        int o = tid & 31, nl = tid >> 5;
        float bo = bias1[o];
        const int nch = N_NODES / 8;   // 6250 exact
        for (int c = lb; c < nch; c += NU1_BLOCKS) {
            __syncthreads();
            for (int idx = tid; idx < 8 * DIN; idx += 256)
                ins[idx >> 5][idx & 31] = x[(size_t)(c * 8 + (idx >> 5)) * DIN + (idx & 31)];
            __syncthreads();
            int n = c * 8 + nl;
            float t = bo;
#pragma unroll
            for (int i = 0; i < DIN; ++i) t += ins[nl][i] * roots[i * H1 + o];
            agg1[(size_t)n * H1 + o] = t;
        }
    } else {
        int lb = bid - EH_BLOCKS - PREP_BLOCKS - NU1_BLOCKS;
        int stride = INIT_BLOCKS * 256;
        int i0 = lb * 256 + tid;
        float4* a2 = (float4*)agg2;
        const int n4 = N_NODES * H2 / 4;
        float4 z4 = {0.f, 0.f, 0.f, 0.f};
        for (int i = i0; i < n4; i += stride) a2[i] = z4;
        for (int i = i0; i < NGRAPH * H2; i += stride) { gmax[i] = __int_as_float(0xff800000); gsum[i] = 0.0f; }
        for (int i = i0; i < NGRAPH; i += stride) gcnt[i] = 0.0f;
    }
}

// ---------------------------------------------------------------- MFMA message + atomic scatter (R4 structure + optional relu on gather)
template <int DOUT, bool RELUG>
__global__ __launch_bounds__(256, 2) void msg_v6_kernel(
    const float* __restrict__ gsrc,          // [N, 32] (agg1 for layer 2, relu applied on the fly)
    const uint32* __restrict__ hpk,          // [E, 32] duplicated-half2
    const int* __restrict__ src, const int* __restrict__ dst,
    const unsigned short* __restrict__ w2h,  // f16 [DOUT][KTOT]
    float* __restrict__ agg)                 // [N, DOUT] pre-seeded with root term
{
    constexpr int NT = DOUT / 16;
    __shared__ __align__(16) uint32 hlds[4][2][32][36];

    const int tid = threadIdx.x;
    const int wave = tid >> 6;
    const int lane = tid & 63;
    const int col = lane & 15;
    const int kq = lane >> 4;

    const int w = blockIdx.x * 4 + wave;
    const int ot = w % NT;
    int it = w / NT;
    const int strideIt = (MSG_BLOCKS * 4) / NT;
    const int NIT = N_EDGES / 32;            // 3125 exact

    f16x8 B[33];
    {
        const unsigned short* bp = w2h + (size_t)(ot * 16 + col) * KTOT + kq * 8;
#pragma unroll
        for (int kk = 0; kk < 33; ++kk)
            B[kk] = *reinterpret_cast<const f16x8*>(bp + kk * 32);
    }
    if (it >= NIT) return;

    int buf = 0;

    int e0 = it * 32;
    int sA = src[e0 + col], sB = src[e0 + 16 + col];
    float4 gA0 = *reinterpret_cast<const float4*>(gsrc + (size_t)sA * DIN + kq * 8);
    float4 gA1 = *reinterpret_cast<const float4*>(gsrc + (size_t)sA * DIN + kq * 8 + 4);
    float4 gB0 = *reinterpret_cast<const float4*>(gsrc + (size_t)sB * DIN + kq * 8);
    float4 gB1 = *reinterpret_cast<const float4*>(gsrc + (size_t)sB * DIN + kq * 8 + 4);
    uint4 hA0 = *reinterpret_cast<const uint4*>(hpk + (size_t)(e0 + col) * EHID + kq * 8);
    uint4 hA1 = *reinterpret_cast<const uint4*>(hpk + (size_t)(e0 + col) * EHID + kq * 8 + 4);
    uint4 hB0 = *reinterpret_cast<const uint4*>(hpk + (size_t)(e0 + 16 + col) * EHID + kq * 8);
    uint4 hB1 = *reinterpret_cast<const uint4*>(hpk + (size_t)(e0 + 16 + col) * EHID + kq * 8 + 4);
    int4 ddA = *reinterpret_cast<const int4*>(dst + e0 + kq * 4);
    int4 ddB = *reinterpret_cast<const int4*>(dst + e0 + 16 + kq * 4);

    int it1 = it + strideIt;
    int s1A = 0, s1B = 0;
    if (it1 < NIT) { s1A = src[it1 * 32 + col]; s1B = src[it1 * 32 + 16 + col]; }

    GF gfA = pack_g8<RELUG>(gA0, gA1);
    GF gfB = pack_g8<RELUG>(gB0, gB1);
    *reinterpret_cast<uint4*>(&hlds[wave][0][col][kq * 8])          = hA0;
    *reinterpret_cast<uint4*>(&hlds[wave][0][col][kq * 8 + 4])      = hA1;
    *reinterpret_cast<uint4*>(&hlds[wave][0][16 + col][kq * 8])     = hB0;
    *reinterpret_cast<uint4*>(&hlds[wave][0][16 + col][kq * 8 + 4]) = hB1;

    for (;;) {
        int it2 = it1 + strideIt;
        int s2A = 0, s2B = 0;
        if (it2 < NIT) { s2A = src[it2 * 32 + col]; s2B = src[it2 * 32 + 16 + col]; }

        const bool nv = (it1 < NIT);
        float4 ngA0, ngA1, ngB0, ngB1;
        uint4 nhA0, nhA1, nhB0, nhB1;
        int4 nddA, nddB;
        if (nv) {
            int ne0 = it1 * 32;
            ngA0 = *reinterpret_cast<const float4*>(gsrc + (size_t)s1A * DIN + kq * 8);
            ngA1 = *reinterpret_cast<const float4*>(gsrc + (size_t)s1A * DIN + kq * 8 + 4);
            ngB0 = *reinterpret_cast<const float4*>(gsrc + (size_t)s1B * DIN + kq * 8);
            ngB1 = *reinterpret_cast<const float4*>(gsrc + (size_t)s1B * DIN + kq * 8 + 4);
            nhA0 = *reinterpret_cast<const uint4*>(hpk + (size_t)(ne0 + col) * EHID + kq * 8);
            nhA1 = *reinterpret_cast<const uint4*>(hpk + (size_t)(ne0 + col) * EHID + kq * 8 + 4);
            nhB0 = *reinterpret_cast<const uint4*>(hpk + (size_t)(ne0 + 16 + col) * EHID + kq * 8);
            nhB1 = *reinterpret_cast<const uint4*>(hpk + (size_t)(ne0 + 16 + col) * EHID + kq * 8 + 4);
            nddA = *reinterpret_cast<const int4*>(dst + ne0 + kq * 4);
            nddB = *reinterpret_cast<const int4*>(dst + ne0 + 16 + kq * 4);
        }

        f32x4 accA = (f32x4){0.f, 0.f, 0.f, 0.f};
        f32x4 accB = (f32x4){0.f, 0.f, 0.f, 0.f};
#pragma unroll
        for (int t = 0; t < 8; ++t) {
            uint4 ha = *reinterpret_cast<const uint4*>(&hlds[wave][buf][col][t * 4]);
            uint4 hb = *reinterpret_cast<const uint4*>(&hlds[wave][buf][16 + col][t * 4]);
            accA = __builtin_amdgcn_mfma_f32_16x16x32_f16(mul_h(ha.x, gfA), B[t * 4 + 0], accA, 0, 0, 0);
            accB = __builtin_amdgcn_mfma_f32_16x16x32_f16(mul_h(hb.x, gfB), B[t * 4 + 0], accB, 0, 0, 0);
            accA = __builtin_amdgcn_mfma_f32_16x16x32_f16(mul_h(ha.y, gfA), B[t * 4 + 1], accA, 0, 0, 0);
            accB = __builtin_amdgcn_mfma_f32_16x16x32_f16(mul_h(hb.y, gfB), B[t * 4 + 1], accB, 0, 0, 0);
            accA = __builtin_amdgcn_mfma_f32_16x16x32_f16(mul_h(ha.z, gfA), B[t * 4 + 2], accA, 0, 0, 0);
            accB = __builtin_amdgcn_mfma_f32_16x16x32_f16(mul_h(hb.z, gfB), B[t * 4 + 2], accB, 0, 0, 0);
            accA = __builtin_amdgcn_mfma_f32_16x16x32_f16(mul_h(ha.w, gfA), B[t * 4 + 3], accA, 0, 0, 0);
            accB = __builtin_amdgcn_mfma_f32_16x16x32_f16(mul_h(hb.w, gfB), B[t * 4 + 3], accB, 0, 0, 0);
        }
        accA = __builtin_amdgcn_mfma_f32_16x16x32_f16(gfA.v, B[32], accA, 0, 0, 0);
        accB = __builtin_amdgcn_mfma_f32_16x16x32_f16(gfB.v, B[32], accB, 0, 0, 0);

        const int oc = ot * 16 + col;
        atomicAdd(&agg[(size_t)ddA.x * DOUT + oc], accA[0]);
        atomicAdd(&agg[(size_t)ddA.y * DOUT + oc], accA[1]);
        atomicAdd(&agg[(size_t)ddA.z * DOUT + oc], accA[2]);
        atomicAdd(&agg[(size_t)ddA.w * DOUT + oc], accA[3]);
        atomicAdd(&agg[(size_t)ddB.x * DOUT + oc], accB[0]);
        atomicAdd(&agg[(size_t)ddB.y * DOUT + oc], accB[1]);
        atomicAdd(&agg[(size_t)ddB.z * DOUT + oc], accB[2]);
        atomicAdd(&agg[(size_t)ddB.w * DOUT + oc], accB[3]);

        if (!nv) break;

        buf ^= 1;
        *reinterpret_cast<uint4*>(&hlds[wave][buf][col][kq * 8])          = nhA0;
        *reinterpret_cast<uint4*>(&hlds[wave][buf][col][kq * 8 + 4])      = nhA1;
        *reinterpret_cast<uint4*>(&hlds[wave][buf][16 + col][kq * 8])     = nhB0;
        *reinterpret_cast<uint4*>(&hlds[wave][buf][16 + col][kq * 8 + 4]) = nhB1;
        gfA = pack_g8<RELUG>(ngA0, ngA1);
        gfB = pack_g8<RELUG>(ngB0, ngB1);
        ddA = nddA; ddB = nddB;
        s1A = s2A; s1B = s2B;
        it = it1; it1 = it2;
    }
}

// ---------------------------------------------------------------- fused layer-2 update + pooling:
// out2[n,o] = relu(agg1[n])@root2[:,o] + agg2[n,o] + bias2[o]; pooled directly (sorted batch runs)
__global__ __launch_bounds__(256) void update2_pool_kernel(
    const float* __restrict__ agg1, const float* __restrict__ root2,
    const float* __restrict__ agg2, const float* __restrict__ bias2,
    const int* __restrict__ batch,
    float* gmax, float* gsum, float* gcnt)
{
    __shared__ float a1[64][DIN + 1];
    __shared__ float r2[DIN * H2];
    __shared__ int bt[64];
    int tid = threadIdx.x;
    int base = blockIdx.x * 64;
    for (int idx = tid; idx < DIN * H2; idx += 256) r2[idx] = root2[idx];
    for (int idx = tid; idx < 64 * DIN; idx += 256) {
        int nn = base + (idx >> 5);
        a1[idx >> 5][idx & 31] = (nn < N_NODES) ? fmaxf(agg1[(size_t)nn * DIN + (idx & 31)], 0.0f) : 0.0f;
    }
    if (tid < 64) bt[tid] = (base + tid < N_NODES) ? batch[base + tid] : -1;
    __syncthreads();

    int o = tid & 63, r = tid >> 6;
    float bo = bias2[o];
    int curb = -1; float s = 0.f, m = __int_as_float(0xff800000); float c = 0.f;
#pragma unroll
    for (int j = 0; j < 16; ++j) {
        int n = base + r * 16 + j;
        if (n >= N_NODES) break;
        int b = bt[r * 16 + j];
        if (b != curb) {
            if (curb >= 0) {
                atomicAdd(&gsum[curb * H2 + o], s);
                atomicMaxF(&gmax[curb * H2 + o], m);
                if (o == 0) atomicAdd(&gcnt[curb], c);
            }
            curb = b; s = 0.f; m = __int_as_float(0xff800000); c = 0.f;
        }
        float v = bo + agg2[(size_t)n * H2 + o];
#pragma unroll
        for (int i = 0; i < DIN; ++i) v += a1[r * 16 + j][i] * r2[i * H2 + o];
        s += v; m = fmaxf(m, v); c += 1.f;
    }
    if (curb >= 0) {
        atomicAdd(&gsum[curb * H2 + o], s);
        atomicMaxF(&gmax[curb * H2 + o], m);
        if (o == 0) atomicAdd(&gcnt[curb], c);
    }
}

// ---------------------------------------------------------------- MLP head
__global__ __launch_bounds__(128) void head_kernel(
    const float* __restrict__ gmax, const float* __restrict__ gsum, const float* __restrict__ gcnt,
    const float* __restrict__ h1w, const float* __restrict__ h1b,
    const float* __restrict__ bn1g, const float* __restrict__ bn1b,
    const float* __restrict__ bn1m, const float* __restrict__ bn1v,
    const float* __restrict__ h2w, const float* __restrict__ h2b,
    const float* __restrict__ bn2g, const float* __restrict__ bn2b,
    const float* __restrict__ bn2m, const float* __restrict__ bn2v,
    const float* __restrict__ h3w, const float* __restrict__ h3b,
    float* __restrict__ out)
{
    __shared__ float feat[2 * H2];
    __shared__ float z1s[H2];
    __shared__ float z2s[H2 / 2];
    int b = blockIdx.x, tid = threadIdx.x;
    float cnt = fmaxf(gcnt[b], 1.0f);
    if (tid < H2) feat[tid] = gmax[b * H2 + tid];
    else          feat[tid] = gsum[b * H2 + (tid - H2)] / cnt;
    __syncthreads();
    if (tid < H2) {
        float acc = h1b[tid];
#pragma unroll
        for (int j = 0; j < 2 * H2; ++j) acc += feat[j] * h1w[j * H2 + tid];
        acc = (acc - bn1m[tid]) * rsqrtf(bn1v[tid] + BN_EPS) * bn1g[tid] + bn1b[tid];
        z1s[tid] = fmaxf(acc, 0.0f);
    }
    __syncthreads();
    if (tid < H2 / 2) {
        float acc = h2b[tid];
#pragma unroll
        for (int j = 0; j < H2; ++j) acc += z1s[j] * h2w[j * (H2 / 2) + tid];
        acc = (acc - bn2m[tid]) * rsqrtf(bn2v[tid] + BN_EPS) * bn2g[tid] + bn2b[tid];
        z2s[tid] = fmaxf(acc, 0.0f);
    }
    __syncthreads();
    if (tid == 0) {
        float acc = h3b[0];
#pragma unroll
        for (int j = 0; j < H2 / 2; ++j) acc += z2s[j] * h3w[j];
        out[b] = acc;
    }
}

// ---------------------------------------------------------------- launch
extern "C" void kernel_launch(void* const* d_in, const int* in_sizes, int n_in,
                              void* d_out, int out_size, void* d_ws, size_t ws_size,
                              hipStream_t stream)
{
    const float* x         = (const float*)d_in[0];
    const int*   ei        = (const int*)d_in[1];
    const float* edge_attr = (const float*)d_in[2];
    const int*   batch     = (const int*)d_in[3];
    const float* e1_w1 = (const float*)d_in[4];
    const float* e1_b1 = (const float*)d_in[5];
    const float* e1_w2 = (const float*)d_in[6];
    const float* e1_b2 = (const float*)d_in[7];
    const float* root1 = (const float*)d_in[8];
    const float* bias1 = (const float*)d_in[9];
    const float* e2_w1 = (const float*)d_in[10];
    const float* e2_b1 = (const float*)d_in[11];
    const float* e2_w2 = (const float*)d_in[12];
    const float* e2_b2 = (const float*)d_in[13];
    const float* root2 = (const float*)d_in[14];
    const float* bias2 = (const float*)d_in[15];
    const float* h1w = (const float*)d_in[16];
    const float* h1b = (const float*)d_in[17];
    const float* bn1g = (const float*)d_in[18];
    const float* bn1b = (const float*)d_in[19];
    const float* bn1m = (const float*)d_in[20];
    const float* bn1v = (const float*)d_in[21];
    const float* h2w = (const float*)d_in[22];
    const float* h2b = (const float*)d_in[23];
    const float* bn2g = (const float*)d_in[24];
    const float* bn2b = (const float*)d_in[25];
    const float* bn2m = (const float*)d_in[26];
    const float* bn2v = (const float*)d_in[27];
    const float* h3w = (const float*)d_in[28];
    const float* h3b = (const float*)d_in[29];
    float* out = (float*)d_out;

    float* ws = (float*)d_ws;
    uint32* hpk1 = (uint32*)ws;                              // E*32 u32
    uint32* hpk2 = hpk1 + (size_t)N_EDGES * EHID;            // E*32 u32
    float* agg1  = (float*)(hpk2 + (size_t)N_EDGES * EHID);  // N*H1
    float* agg2  = agg1 + (size_t)N_NODES * H1;              // N*H2
    float* gmaxb = agg2 + (size_t)N_NODES * H2;              // NGRAPH*H2
    float* gsumb = gmaxb + NGRAPH * H2;                      // NGRAPH*H2
    float* gcntb = gsumb + NGRAPH * H2;                      // NGRAPH (+pad)
    unsigned short* w2h1 = (unsigned short*)(gcntb + 256);   // H1*KTOT f16
    unsigned short* w2h2 = w2h1 + (size_t)H1 * KTOT;         // H2*KTOT f16

    const int* srcp = ei;
    const int* dstp = ei + N_EDGES;

    prologue_kernel<<<EH_BLOCKS + PREP_BLOCKS + NU1_BLOCKS + INIT_BLOCKS, 256, 0, stream>>>(
        edge_attr, e1_w1, e1_b1, e2_w1, e2_b1, e1_w2, e1_b2, e2_w2, e2_b2,
        x, root1, bias1,
        hpk1, hpk2, w2h1, w2h2, agg1, agg2, gmaxb, gsumb, gcntb);

    msg_v6_kernel<H1, false><<<MSG_BLOCKS, 256, 0, stream>>>(x, hpk1, srcp, dstp, w2h1, agg1);
    msg_v6_kernel<H2, true><<<MSG_BLOCKS, 256, 0, stream>>>(agg1, hpk2, srcp, dstp, w2h2, agg2);

    update2_pool_kernel<<<(N_NODES + 63) / 64, 256, 0, stream>>>(
        agg1, root2, agg2, bias2, batch, gmaxb, gsumb, gcntb);

    head_kernel<<<NGRAPH, 128, 0, stream>>>(gmaxb, gsumb, gcntb,
                                            h1w, h1b, bn1g, bn1b, bn1m, bn1v,
                                            h2w, h2b, bn2g, bn2b, bn2m, bn2v,
                                            h3w, h3b, out);
}